// Round 6
// baseline (526.860 us; speedup 1.0000x reference)
//
#include <hip/hip_runtime.h>
#include <cstddef>
#include <cstdint>

#define E_TOTAL 3200000
#define N_NODES 100000
#define N_RELS 50
#define N_BASES 16
#define HD 16
#define OD 8
#define NTHR 256

#define NBKT 196      // coarse buckets: dst >> 9 (512 dsts each)
#define BKT_CAP 18000
#define P1_BLOCKS 256
#define P1_CHUNK 12500
#define NTILE 391     // ceil(100000/256)
#define RPB1 10       // rels per block in k_emb1m (5 groups)
#define RPB2 25       // rels per block in k_emb2m (2 groups)

typedef unsigned int u32;

__device__ __forceinline__ float bl16(u32 u) { return __uint_as_float(u << 16); }
__device__ __forceinline__ float bh16(u32 u) { return __uint_as_float(u & 0xffff0000u); }
__device__ __forceinline__ u32 packbf(float x0, float x1) {
    u32 a = __float_as_uint(x0), b = __float_as_uint(x1);
    a = (a + 0x7fffu + ((a >> 16) & 1u)) >> 16;
    b = (b + 0x7fffu + ((b >> 16) & 1u)) >> 16;
    return a | (b << 16);
}

// ---------------- basis-combined dense weights (fp32, in ws) ----------------
__global__ __launch_bounds__(NTHR) void k_wr(const float* __restrict__ W1, const float* __restrict__ C1,
                                             const float* __restrict__ W2, const float* __restrict__ C2,
                                             float* __restrict__ Wr1, float* __restrict__ Wr2) {
    int idx = blockIdx.x * NTHR + threadIdx.x;
    const int n1 = N_RELS * 256;
    if (idx < n1) {
        int r = idx >> 8, io = idx & 255;
        float acc = 0.f;
        #pragma unroll
        for (int b = 0; b < N_BASES; ++b)
            acc = fmaf(C1[r * N_BASES + b], W1[b * 256 + io], acc);
        Wr1[idx] = acc;
    } else if (idx < n1 + N_RELS * 128) {
        int j = idx - n1;
        int r = j >> 7, io = j & 127;
        float acc = 0.f;
        #pragma unroll
        for (int b = 0; b < N_BASES; ++b)
            acc = fmaf(C2[r * N_BASES + b], W2[b * 128 + io], acc);
        Wr2[j] = acc;
    }
}

// ================= two-level dst-sort (write-amplification-free) =================

__global__ __launch_bounds__(NTHR) void k_p1(const int* __restrict__ esrc, const int* __restrict__ edst,
                                             const int* __restrict__ erel, const float* __restrict__ enorm,
                                             int* __restrict__ bhead, uint2* __restrict__ tmp) {
    __shared__ int lcnt[NBKT], lbase[NBKT], lcur[NBKT];
    int tid = threadIdx.x;
    for (int i = tid; i < NBKT; i += NTHR) { lcnt[i] = 0; lcur[i] = 0; }
    __syncthreads();
    int e0 = blockIdx.x * P1_CHUNK;
    for (int i = tid; i < P1_CHUNK; i += NTHR)
        atomicAdd(&lcnt[edst[e0 + i] >> 9], 1);
    __syncthreads();
    for (int i = tid; i < NBKT; i += NTHR)
        lbase[i] = atomicAdd(&bhead[i], lcnt[i]);
    __syncthreads();
    for (int i = tid; i < P1_CHUNK; i += NTHR) {
        int e = e0 + i;
        int d = edst[e];
        int b = d >> 9;
        int pos = b * BKT_CAP + lbase[b] + atomicAdd(&lcur[b], 1);
        tmp[pos] = make_uint2((u32)esrc[e] | ((u32)erel[e] << 17) | ((u32)(d & 511) << 23),
                              __float_as_uint(enorm[e]));
    }
}

__global__ void k_bscan(const int* __restrict__ bhead, int* __restrict__ bfinal) {
    __shared__ int s[256];
    int tid = threadIdx.x;
    int v = (tid < NBKT) ? bhead[tid] : 0;
    s[tid] = v;
    __syncthreads();
    for (int off = 1; off < 256; off <<= 1) {
        int t = (tid >= off) ? s[tid - off] : 0;
        __syncthreads();
        s[tid] += t;
        __syncthreads();
    }
    if (tid < NBKT) bfinal[tid] = s[tid] - v;  // exclusive
}

__global__ __launch_bounds__(NTHR) void k_p2(const uint2* __restrict__ tmp, const int* __restrict__ bhead,
                                             const int* __restrict__ bfinal, uint2* __restrict__ rec,
                                             int* __restrict__ row_ptr) {
    int b = blockIdx.x;
    int cnt = bhead[b];
    int gbase = bfinal[b];
    __shared__ int dcnt[512], dscan[512];
    int tid = threadIdx.x;
    dcnt[tid] = 0;
    dcnt[tid + 256] = 0;
    __syncthreads();
    const uint2* tb = tmp + (size_t)b * BKT_CAP;
    for (int i = tid; i < cnt; i += NTHR)
        atomicAdd(&dcnt[tb[i].x >> 23], 1);
    __syncthreads();
    dscan[tid] = dcnt[tid];
    dscan[tid + 256] = dcnt[tid + 256];
    __syncthreads();
    for (int off = 1; off < 512; off <<= 1) {
        int v0 = (tid >= off) ? dscan[tid - off] : 0;
        int v1 = (tid + 256 >= off) ? dscan[tid + 256 - off] : 0;
        __syncthreads();
        dscan[tid] += v0;
        dscan[tid + 256] += v1;
        __syncthreads();
    }
    int d0 = b << 9;
    #pragma unroll
    for (int k = 0; k < 2; ++k) {
        int dl = tid + k * 256;
        int excl = gbase + dscan[dl] - dcnt[dl];
        int d = d0 + dl;
        if (d < N_NODES) row_ptr[d] = excl;
        dscan[dl] = excl;
    }
    if (b == NBKT - 1 && tid == 0) row_ptr[N_NODES] = E_TOTAL;
    __syncthreads();
    for (int i = tid; i < cnt; i += NTHR) {
        uint2 t = tb[i];
        int pos = atomicAdd(&dscan[t.x >> 23], 1);
        rec[pos] = make_uint2(t.x & 0x7FFFFFu, t.y);
    }
}

// ================= dense embedding tables =================

// emb0[r][n][h] = sum_b C0[r,b]*W0[b,n,h], bf16.
__global__ __launch_bounds__(NTHR) void k_emb0(const float* __restrict__ W0, const float* __restrict__ C0,
                                               ushort* __restrict__ emb) {
    int t = threadIdx.x;
    size_t base = (size_t)blockIdx.x * 256 + t;  // n*16+h
    float w[16];
    #pragma unroll
    for (int b = 0; b < 16; ++b) w[b] = W0[(size_t)b * (N_NODES * HD) + base];
    __shared__ float c[N_RELS * 16];
    for (int i = t; i < N_RELS * 16; i += NTHR) c[i] = C0[i];
    __syncthreads();
    for (int r = 0; r < N_RELS; ++r) {
        const float* cr = c + r * 16;
        float v = 0.f;
        #pragma unroll
        for (int b = 0; b < 16; ++b) v = fmaf(cr[b], w[b], v);
        u32 x = __float_as_uint(v);
        x = (x + 0x7fffu + ((x >> 16) & 1u)) >> 16;
        emb[(size_t)r * (N_NODES * HD) + base] = (ushort)x;
    }
}

// gather-accumulate 16-dim bf16 rows by (rel,src), relu-fused, fp32 out.
__global__ __launch_bounds__(NTHR) void k_g16(const uint2* __restrict__ rec, const int* __restrict__ row_ptr,
                                              const ushort* __restrict__ tbl, float* __restrict__ out) {
    int lane = threadIdx.x & 63;
    int g = lane >> 3, l = lane & 7;
    int wave = (blockIdx.x * NTHR + threadIdx.x) >> 6;
    int nw = (gridDim.x * NTHR) >> 6;
    for (int d = wave; d < N_NODES; d += nw) {
        int s0 = row_ptr[d], s1 = row_ptr[d + 1];
        float a0 = 0.f, a1 = 0.f;
        for (int j = s0 + g; j < s1; j += 8) {
            uint2 rc = rec[j];
            int src = rc.x & 0x1FFFF;
            int rel = rc.x >> 17;
            float nm = __uint_as_float(rc.y);
            u32 q = *(const u32*)(tbl + ((size_t)rel * N_NODES + src) * HD + l * 2);
            a0 = fmaf(nm, bl16(q), a0);
            a1 = fmaf(nm, bh16(q), a1);
        }
        a0 += __shfl_xor(a0, 8);  a1 += __shfl_xor(a1, 8);
        a0 += __shfl_xor(a0, 16); a1 += __shfl_xor(a1, 16);
        a0 += __shfl_xor(a0, 32); a1 += __shfl_xor(a1, 32);
        if (lane < 8)
            *(float2*)(out + (size_t)d * HD + l * 2) = make_float2(fmaxf(a0, 0.f), fmaxf(a1, 0.f));
    }
}

// emb1[r][n][o] = sum_i h[n,i]*Wr1[r,i,o], bf16 out.
// Node-tile-major: block loads its 256-node h-tile ONCE (registers), loops RPB1 rels.
__global__ __launch_bounds__(NTHR) void k_emb1m(const float* __restrict__ Wr1, const float* __restrict__ h,
                                                ushort* __restrict__ emb) {
    int grp = blockIdx.x / NTILE;   // rel group: [grp*RPB1, grp*RPB1+RPB1)
    int tile = blockIdx.x % NTILE;
    __shared__ float w[RPB1 * 256];  // 10 KB
    for (int i = threadIdx.x; i < RPB1 * 256; i += NTHR)
        w[i] = Wr1[grp * (RPB1 * 256) + i];
    __syncthreads();
    int n = tile * NTHR + threadIdx.x;
    if (n >= N_NODES) return;
    const float4* hp = (const float4*)(h + (size_t)n * HD);
    float4 a0 = hp[0], a1 = hp[1], a2 = hp[2], a3 = hp[3];
    float hv[16] = {a0.x, a0.y, a0.z, a0.w, a1.x, a1.y, a1.z, a1.w,
                    a2.x, a2.y, a2.z, a2.w, a3.x, a3.y, a3.z, a3.w};
    for (int rr = 0; rr < RPB1; ++rr) {
        const float* wr = w + rr * 256;
        float acc[16];
        #pragma unroll
        for (int o = 0; o < 16; ++o) acc[o] = 0.f;
        #pragma unroll
        for (int i = 0; i < 16; ++i) {
            const float4* wp = (const float4*)(wr + i * 16);  // uniform -> LDS broadcast
            float4 w0 = wp[0], w1 = wp[1], w2 = wp[2], w3 = wp[3];
            float hi = hv[i];
            acc[0] = fmaf(hi, w0.x, acc[0]);   acc[1] = fmaf(hi, w0.y, acc[1]);
            acc[2] = fmaf(hi, w0.z, acc[2]);   acc[3] = fmaf(hi, w0.w, acc[3]);
            acc[4] = fmaf(hi, w1.x, acc[4]);   acc[5] = fmaf(hi, w1.y, acc[5]);
            acc[6] = fmaf(hi, w1.z, acc[6]);   acc[7] = fmaf(hi, w1.w, acc[7]);
            acc[8] = fmaf(hi, w2.x, acc[8]);   acc[9] = fmaf(hi, w2.y, acc[9]);
            acc[10] = fmaf(hi, w2.z, acc[10]); acc[11] = fmaf(hi, w2.w, acc[11]);
            acc[12] = fmaf(hi, w3.x, acc[12]); acc[13] = fmaf(hi, w3.y, acc[13]);
            acc[14] = fmaf(hi, w3.z, acc[14]); acc[15] = fmaf(hi, w3.w, acc[15]);
        }
        u32 p[8];
        #pragma unroll
        for (int k = 0; k < 8; ++k) p[k] = packbf(acc[2 * k], acc[2 * k + 1]);
        uint4* op = (uint4*)(emb + ((size_t)(grp * RPB1 + rr) * N_NODES + n) * HD);
        op[0] = make_uint4(p[0], p[1], p[2], p[3]);
        op[1] = make_uint4(p[4], p[5], p[6], p[7]);
    }
}

// emb2[r][n][o] = sum_i h[n,i]*Wr2[r,i,o] (o<8), bf16 out. Node-tile-major.
__global__ __launch_bounds__(NTHR) void k_emb2m(const float* __restrict__ Wr2, const float* __restrict__ h,
                                                ushort* __restrict__ emb) {
    int grp = blockIdx.x / NTILE;   // 0 or 1: rels [grp*RPB2, grp*RPB2+RPB2)
    int tile = blockIdx.x % NTILE;
    __shared__ float w[RPB2 * 128];  // 12.8 KB
    for (int i = threadIdx.x; i < RPB2 * 128; i += NTHR)
        w[i] = Wr2[grp * (RPB2 * 128) + i];
    __syncthreads();
    int n = tile * NTHR + threadIdx.x;
    if (n >= N_NODES) return;
    const float4* hp = (const float4*)(h + (size_t)n * HD);
    float4 a0 = hp[0], a1 = hp[1], a2 = hp[2], a3 = hp[3];
    float hv[16] = {a0.x, a0.y, a0.z, a0.w, a1.x, a1.y, a1.z, a1.w,
                    a2.x, a2.y, a2.z, a2.w, a3.x, a3.y, a3.z, a3.w};
    for (int rr = 0; rr < RPB2; ++rr) {
        const float* wr = w + rr * 128;
        float acc[8];
        #pragma unroll
        for (int o = 0; o < 8; ++o) acc[o] = 0.f;
        #pragma unroll
        for (int i = 0; i < 16; ++i) {
            const float4* wp = (const float4*)(wr + i * 8);  // uniform -> LDS broadcast
            float4 w0 = wp[0], w1 = wp[1];
            float hi = hv[i];
            acc[0] = fmaf(hi, w0.x, acc[0]); acc[1] = fmaf(hi, w0.y, acc[1]);
            acc[2] = fmaf(hi, w0.z, acc[2]); acc[3] = fmaf(hi, w0.w, acc[3]);
            acc[4] = fmaf(hi, w1.x, acc[4]); acc[5] = fmaf(hi, w1.y, acc[5]);
            acc[6] = fmaf(hi, w1.z, acc[6]); acc[7] = fmaf(hi, w1.w, acc[7]);
        }
        u32 p[4];
        #pragma unroll
        for (int k = 0; k < 4; ++k) p[k] = packbf(acc[2 * k], acc[2 * k + 1]);
        *(uint4*)(emb + ((size_t)(grp * RPB2 + rr) * N_NODES + n) * OD) = make_uint4(p[0], p[1], p[2], p[3]);
    }
}

// gather 8-dim bf16 rows + fused softmax. 16 edge-groups x 4 lanes.
__global__ __launch_bounds__(NTHR) void k_g8sm(const uint2* __restrict__ rec, const int* __restrict__ row_ptr,
                                               const ushort* __restrict__ tbl, float* __restrict__ out) {
    int lane = threadIdx.x & 63;
    int g = lane >> 2, l = lane & 3;
    int wave = (blockIdx.x * NTHR + threadIdx.x) >> 6;
    int nw = (gridDim.x * NTHR) >> 6;
    for (int d = wave; d < N_NODES; d += nw) {
        int s0 = row_ptr[d], s1 = row_ptr[d + 1];
        float a0 = 0.f, a1 = 0.f;
        for (int j = s0 + g; j < s1; j += 16) {
            uint2 rc = rec[j];
            int src = rc.x & 0x1FFFF;
            int rel = rc.x >> 17;
            float nm = __uint_as_float(rc.y);
            u32 q = *(const u32*)(tbl + ((size_t)rel * N_NODES + src) * OD + l * 2);
            a0 = fmaf(nm, bl16(q), a0);
            a1 = fmaf(nm, bh16(q), a1);
        }
        a0 += __shfl_xor(a0, 4);  a1 += __shfl_xor(a1, 4);
        a0 += __shfl_xor(a0, 8);  a1 += __shfl_xor(a1, 8);
        a0 += __shfl_xor(a0, 16); a1 += __shfl_xor(a1, 16);
        a0 += __shfl_xor(a0, 32); a1 += __shfl_xor(a1, 32);
        float mm = fmaxf(a0, a1);
        mm = fmaxf(mm, __shfl_xor(mm, 1));
        mm = fmaxf(mm, __shfl_xor(mm, 2));
        float e0 = __expf(a0 - mm), e1 = __expf(a1 - mm);
        float s = e0 + e1;
        s += __shfl_xor(s, 1);
        s += __shfl_xor(s, 2);
        float inv = 1.0f / s;
        if (lane < 4)
            *(float2*)(out + (size_t)d * OD + l * 2) = make_float2(e0 * inv, e1 * inv);
    }
}

// ======= TIER B fallback (atomics, 16.1 MB) =======
#define NBLK 2560

__device__ __forceinline__ void fma4(float* acc, float c, float4 w) {
    acc[0] = fmaf(c, w.x, acc[0]);
    acc[1] = fmaf(c, w.y, acc[1]);
    acc[2] = fmaf(c, w.z, acc[2]);
    acc[3] = fmaf(c, w.w, acc[3]);
}

__global__ __launch_bounds__(NTHR) void k_l0_old(const int* __restrict__ esrc, const int* __restrict__ edst,
                                                 const int* __restrict__ erel, const float* __restrict__ enorm,
                                                 const float* __restrict__ W0, const float* __restrict__ C0,
                                                 float* __restrict__ h0) {
    for (int e = blockIdx.x * NTHR + threadIdx.x; e < E_TOTAL; e += NBLK * NTHR) {
        int s = esrc[e], d = edst[e], r = erel[e];
        float nm = enorm[e];
        const float4* cp = reinterpret_cast<const float4*>(C0 + r * N_BASES);
        float4 c0 = cp[0], c1 = cp[1], c2 = cp[2], c3 = cp[3];
        float coef[16] = {c0.x, c0.y, c0.z, c0.w, c1.x, c1.y, c1.z, c1.w,
                          c2.x, c2.y, c2.z, c2.w, c3.x, c3.y, c3.z, c3.w};
        float acc[16];
        #pragma unroll
        for (int h = 0; h < 16; ++h) acc[h] = 0.f;
        const float* wbase = W0 + (size_t)s * HD;
        #pragma unroll
        for (int b = 0; b < N_BASES; ++b) {
            const float4* wp = reinterpret_cast<const float4*>(wbase + (size_t)b * (N_NODES * HD));
            float cb = coef[b];
            fma4(acc + 0, cb, wp[0]);
            fma4(acc + 4, cb, wp[1]);
            fma4(acc + 8, cb, wp[2]);
            fma4(acc + 12, cb, wp[3]);
        }
        float* outp = h0 + (size_t)d * HD;
        #pragma unroll
        for (int h = 0; h < 16; ++h) atomicAdd(outp + h, nm * acc[h]);
    }
}

__global__ __launch_bounds__(NTHR) void k_l1_old(const int* __restrict__ esrc, const int* __restrict__ edst,
                                                 const int* __restrict__ erel, const float* __restrict__ enorm,
                                                 const float* __restrict__ h0, const float* __restrict__ Wr1,
                                                 float* __restrict__ h1) {
    __shared__ float w[N_RELS * 260];
    for (int i = threadIdx.x; i < N_RELS * 256; i += NTHR) {
        int r = i >> 8, rest = i & 255;
        w[r * 260 + rest] = Wr1[i];
    }
    __syncthreads();
    for (int e = blockIdx.x * NTHR + threadIdx.x; e < E_TOTAL; e += NBLK * NTHR) {
        int s = esrc[e], d = edst[e], r = erel[e];
        float nm = enorm[e];
        const float4* hp = reinterpret_cast<const float4*>(h0 + (size_t)s * HD);
        float4 hv0 = hp[0], hv1 = hp[1], hv2 = hp[2], hv3 = hp[3];
        float hs[16] = {fmaxf(hv0.x, 0.f), fmaxf(hv0.y, 0.f), fmaxf(hv0.z, 0.f), fmaxf(hv0.w, 0.f),
                        fmaxf(hv1.x, 0.f), fmaxf(hv1.y, 0.f), fmaxf(hv1.z, 0.f), fmaxf(hv1.w, 0.f),
                        fmaxf(hv2.x, 0.f), fmaxf(hv2.y, 0.f), fmaxf(hv2.z, 0.f), fmaxf(hv2.w, 0.f),
                        fmaxf(hv3.x, 0.f), fmaxf(hv3.y, 0.f), fmaxf(hv3.z, 0.f), fmaxf(hv3.w, 0.f)};
        float acc[16];
        #pragma unroll
        for (int h = 0; h < 16; ++h) acc[h] = 0.f;
        const float* wr = w + r * 260;
        #pragma unroll
        for (int i = 0; i < 16; ++i) {
            float hi = hs[i];
            const float4* wp = reinterpret_cast<const float4*>(wr + i * 16);
            fma4(acc + 0, hi, wp[0]);
            fma4(acc + 4, hi, wp[1]);
            fma4(acc + 8, hi, wp[2]);
            fma4(acc + 12, hi, wp[3]);
        }
        float* outp = h1 + (size_t)d * HD;
        #pragma unroll
        for (int h = 0; h < 16; ++h) atomicAdd(outp + h, nm * acc[h]);
    }
}

__global__ __launch_bounds__(NTHR) void k_l2_old(const int* __restrict__ esrc, const int* __restrict__ edst,
                                                 const int* __restrict__ erel, const float* __restrict__ enorm,
                                                 const float* __restrict__ h1, const float* __restrict__ Wr2,
                                                 float* __restrict__ h2) {
    __shared__ float w[N_RELS * 132];
    for (int i = threadIdx.x; i < N_RELS * 128; i += NTHR) {
        int r = i >> 7, rest = i & 127;
        w[r * 132 + rest] = Wr2[i];
    }
    __syncthreads();
    for (int e = blockIdx.x * NTHR + threadIdx.x; e < E_TOTAL; e += NBLK * NTHR) {
        int s = esrc[e], d = edst[e], r = erel[e];
        float nm = enorm[e];
        const float4* hp = reinterpret_cast<const float4*>(h1 + (size_t)s * HD);
        float4 hv0 = hp[0], hv1 = hp[1], hv2 = hp[2], hv3 = hp[3];
        float hs[16] = {fmaxf(hv0.x, 0.f), fmaxf(hv0.y, 0.f), fmaxf(hv0.z, 0.f), fmaxf(hv0.w, 0.f),
                        fmaxf(hv1.x, 0.f), fmaxf(hv1.y, 0.f), fmaxf(hv1.z, 0.f), fmaxf(hv1.w, 0.f),
                        fmaxf(hv2.x, 0.f), fmaxf(hv2.y, 0.f), fmaxf(hv2.z, 0.f), fmaxf(hv2.w, 0.f),
                        fmaxf(hv3.x, 0.f), fmaxf(hv3.y, 0.f), fmaxf(hv3.z, 0.f), fmaxf(hv3.w, 0.f)};
        float acc[8];
        #pragma unroll
        for (int h = 0; h < 8; ++h) acc[h] = 0.f;
        const float* wr = w + r * 132;
        #pragma unroll
        for (int i = 0; i < 16; ++i) {
            float hi = hs[i];
            const float4* wp = reinterpret_cast<const float4*>(wr + i * 8);
            fma4(acc + 0, hi, wp[0]);
            fma4(acc + 4, hi, wp[1]);
        }
        float* outp = h2 + (size_t)d * OD;
        #pragma unroll
        for (int h = 0; h < 8; ++h) atomicAdd(outp + h, nm * acc[h]);
    }
}

__global__ __launch_bounds__(NTHR) void k_softmax(const float* __restrict__ h2, float* __restrict__ out) {
    int n = blockIdx.x * NTHR + threadIdx.x;
    if (n >= N_NODES) return;
    const float4* p = reinterpret_cast<const float4*>(h2 + (size_t)n * OD);
    float4 a = p[0], b = p[1];
    float v[8] = {a.x, a.y, a.z, a.w, b.x, b.y, b.z, b.w};
    float m = v[0];
    #pragma unroll
    for (int i = 1; i < 8; ++i) m = fmaxf(m, v[i]);
    float ssum = 0.f;
    #pragma unroll
    for (int i = 0; i < 8; ++i) {
        v[i] = __expf(v[i] - m);
        ssum += v[i];
    }
    float inv = 1.0f / ssum;
    float4* q = reinterpret_cast<float4*>(out + (size_t)n * OD);
    q[0] = make_float4(v[0] * inv, v[1] * inv, v[2] * inv, v[3] * inv);
    q[1] = make_float4(v[4] * inv, v[5] * inv, v[6] * inv, v[7] * inv);
}

// =========================================================================

extern "C" void kernel_launch(void* const* d_in, const int* in_sizes, int n_in,
                              void* d_out, int out_size, void* d_ws, size_t ws_size,
                              hipStream_t stream) {
    const int* esrc = (const int*)d_in[0];
    const int* edst = (const int*)d_in[1];
    const int* erel = (const int*)d_in[2];
    const float* enorm = (const float*)d_in[3];
    const float* W0 = (const float*)d_in[4];
    const float* C0 = (const float*)d_in[5];
    const float* W1 = (const float*)d_in[6];
    const float* C1 = (const float*)d_in[7];
    const float* W2 = (const float*)d_in[8];
    const float* C2 = (const float*)d_in[9];
    const int nsb = (N_NODES + NTHR - 1) / NTHR;  // 391

    if (ws_size >= (size_t)201000000) {
        char* wsb = (char*)d_ws;
        ushort* emb = (ushort*)wsb;                       // 160,000,000 B (L0/L1 tables; L2 table reuses first 80 MB)
        uint2* tmp = (uint2*)wsb;                         //  28,224,000 B (aliases emb; used before emb0)
        uint2* rec = (uint2*)(wsb + 160000000);           //  25,600,000
        float* h0 = (float*)(wsb + 185600000);            //   6,400,000
        float* h1 = (float*)(wsb + 192000000);            //   6,400,000
        float* Wr1 = (float*)(wsb + 198400000);           //      51,200
        float* Wr2 = (float*)(wsb + 198451200);           //      25,600
        int* row_ptr = (int*)(wsb + 198476800);           //     400,004
        int* bhead = (int*)(wsb + 198876804);             //         784
        int* bfinal = (int*)(wsb + 198877588);            //         784

        hipMemsetAsync(bhead, 0, NBKT * sizeof(int), stream);
        k_p1<<<P1_BLOCKS, NTHR, 0, stream>>>(esrc, edst, erel, enorm, bhead, tmp);
        k_bscan<<<1, 256, 0, stream>>>(bhead, bfinal);
        k_p2<<<NBKT, NTHR, 0, stream>>>(tmp, bhead, bfinal, rec, row_ptr);
        k_wr<<<75, NTHR, 0, stream>>>(W1, C1, W2, C2, Wr1, Wr2);

        k_emb0<<<N_NODES * HD / NTHR, NTHR, 0, stream>>>(W0, C0, emb);
        k_g16<<<6250, NTHR, 0, stream>>>(rec, row_ptr, emb, h0);
        k_emb1m<<<5 * NTILE, NTHR, 0, stream>>>(Wr1, h0, emb);
        k_g16<<<6250, NTHR, 0, stream>>>(rec, row_ptr, emb, h1);
        k_emb2m<<<2 * NTILE, NTHR, 0, stream>>>(Wr2, h1, emb);
        k_g8sm<<<6250, NTHR, 0, stream>>>(rec, row_ptr, emb, (float*)d_out);
    } else {
        // ---- Tier B: atomics fallback ----
        float* ws = (float*)d_ws;
        float* h0 = ws;
        float* h1 = ws + 1600000;
        float* h2 = ws + 3200000;
        float* Wr1 = ws + 4000000;
        float* Wr2 = ws + 4012800;

        hipMemsetAsync(h0, 0, (size_t)4000000 * sizeof(float), stream);
        k_wr<<<75, NTHR, 0, stream>>>(W1, C1, W2, C2, Wr1, Wr2);
        k_l0_old<<<NBLK, NTHR, 0, stream>>>(esrc, edst, erel, enorm, W0, C0, h0);
        k_l1_old<<<NBLK, NTHR, 0, stream>>>(esrc, edst, erel, enorm, h0, Wr1, h1);
        k_l2_old<<<NBLK, NTHR, 0, stream>>>(esrc, edst, erel, enorm, h1, Wr2, h2);
        k_softmax<<<nsb, NTHR, 0, stream>>>(h2, (float*)d_out);
    }
}

// Round 7
// 509.550 us; speedup vs baseline: 1.0340x; 1.0340x over previous
//
#include <hip/hip_runtime.h>
#include <cstddef>
#include <cstdint>

#define E_TOTAL 3200000
#define N_NODES 100000
#define N_RELS 50
#define N_BASES 16
#define HD 16
#define OD 8
#define NTHR 256

#define NBKT 196       // coarse buckets: dst >> 9 (512 dsts each)
#define BKT_CAP 18000
#define P1_BLOCKS 1024
#define P1_CHUNK 3125  // 1024*3125 = 3.2M
#define NTILE 391      // ceil(100000/256)
#define NT4 98         // ceil(100000/1024)
#define RPB1 10        // rels per block in k_emb1q (5 groups)
#define RPB2 5         // rels per block in k_emb2q (10 groups)

typedef unsigned int u32;

__device__ __forceinline__ float bl16(u32 u) { return __uint_as_float(u << 16); }
__device__ __forceinline__ float bh16(u32 u) { return __uint_as_float(u & 0xffff0000u); }
__device__ __forceinline__ u32 packbf(float x0, float x1) {
    u32 a = __float_as_uint(x0), b = __float_as_uint(x1);
    a = (a + 0x7fffu + ((a >> 16) & 1u)) >> 16;
    b = (b + 0x7fffu + ((b >> 16) & 1u)) >> 16;
    return a | (b << 16);
}
// single-instruction bf16 pair pack (RNE), gfx950 [T12, m214v22]
__device__ __forceinline__ u32 cvtpk(float x0, float x1) {
    u32 r;
    asm("v_cvt_pk_bf16_f32 %0, %1, %2" : "=v"(r) : "v"(x0), "v"(x1));
    return r;
}

// ---------------- basis-combined dense weights (fp32, in ws) ----------------
__global__ __launch_bounds__(NTHR) void k_wr(const float* __restrict__ W1, const float* __restrict__ C1,
                                             const float* __restrict__ W2, const float* __restrict__ C2,
                                             float* __restrict__ Wr1, float* __restrict__ Wr2) {
    int idx = blockIdx.x * NTHR + threadIdx.x;
    const int n1 = N_RELS * 256;
    if (idx < n1) {
        int r = idx >> 8, io = idx & 255;
        float acc = 0.f;
        #pragma unroll
        for (int b = 0; b < N_BASES; ++b)
            acc = fmaf(C1[r * N_BASES + b], W1[b * 256 + io], acc);
        Wr1[idx] = acc;
    } else if (idx < n1 + N_RELS * 128) {
        int j = idx - n1;
        int r = j >> 7, io = j & 127;
        float acc = 0.f;
        #pragma unroll
        for (int b = 0; b < N_BASES; ++b)
            acc = fmaf(C2[r * N_BASES + b], W2[b * 128 + io], acc);
        Wr2[j] = acc;
    }
}

// ================= two-level dst-sort =================
// bhead is padded: one counter per 16 ints (64 B line) to avoid atomic line ping-pong.

__global__ __launch_bounds__(NTHR) void k_p1(const int* __restrict__ esrc, const int* __restrict__ edst,
                                             const int* __restrict__ erel, const float* __restrict__ enorm,
                                             int* __restrict__ bhead, uint2* __restrict__ tmp) {
    __shared__ int lcnt[NBKT], lbase[NBKT], lcur[NBKT];
    int tid = threadIdx.x;
    for (int i = tid; i < NBKT; i += NTHR) { lcnt[i] = 0; lcur[i] = 0; }
    __syncthreads();
    int e0 = blockIdx.x * P1_CHUNK;
    for (int i = tid; i < P1_CHUNK; i += NTHR)
        atomicAdd(&lcnt[edst[e0 + i] >> 9], 1);
    __syncthreads();
    for (int i = tid; i < NBKT; i += NTHR)
        lbase[i] = atomicAdd(&bhead[i * 16], lcnt[i]);
    __syncthreads();
    for (int i = tid; i < P1_CHUNK; i += NTHR) {
        int e = e0 + i;
        int d = edst[e];
        int b = d >> 9;
        int pos = b * BKT_CAP + lbase[b] + atomicAdd(&lcur[b], 1);
        tmp[pos] = make_uint2((u32)esrc[e] | ((u32)erel[e] << 17) | ((u32)(d & 511) << 23),
                              __float_as_uint(enorm[e]));
    }
}

__global__ void k_bscan(const int* __restrict__ bhead, int* __restrict__ bfinal) {
    __shared__ int s[256];
    int tid = threadIdx.x;
    int v = (tid < NBKT) ? bhead[tid * 16] : 0;
    s[tid] = v;
    __syncthreads();
    for (int off = 1; off < 256; off <<= 1) {
        int t = (tid >= off) ? s[tid - off] : 0;
        __syncthreads();
        s[tid] += t;
        __syncthreads();
    }
    if (tid < NBKT) bfinal[tid] = s[tid] - v;  // exclusive
}

__global__ __launch_bounds__(1024) void k_p2(const uint2* __restrict__ tmp, const int* __restrict__ bhead,
                                             const int* __restrict__ bfinal, uint2* __restrict__ rec,
                                             int* __restrict__ row_ptr) {
    int b = blockIdx.x;
    int cnt = bhead[b * 16];
    int gbase = bfinal[b];
    __shared__ int dcnt[512], dscan[512];
    int tid = threadIdx.x;
    if (tid < 512) dcnt[tid] = 0;
    __syncthreads();
    const uint2* tb = tmp + (size_t)b * BKT_CAP;
    for (int i = tid; i < cnt; i += 1024)
        atomicAdd(&dcnt[tb[i].x >> 23], 1);
    __syncthreads();
    if (tid < 512) dscan[tid] = dcnt[tid];
    __syncthreads();
    for (int off = 1; off < 512; off <<= 1) {
        int v = (tid >= off && tid < 512) ? dscan[tid - off] : 0;
        __syncthreads();
        if (tid < 512) dscan[tid] += v;
        __syncthreads();
    }
    if (tid < 512) {
        int excl = gbase + dscan[tid] - dcnt[tid];
        int d = (b << 9) + tid;
        if (d < N_NODES) row_ptr[d] = excl;
        dscan[tid] = excl;  // becomes scatter cursor
    }
    if (b == NBKT - 1 && tid == 0) row_ptr[N_NODES] = E_TOTAL;
    __syncthreads();
    for (int i = tid; i < cnt; i += 1024) {
        uint2 t = tb[i];
        int pos = atomicAdd(&dscan[t.x >> 23], 1);
        rec[pos] = make_uint2(t.x & 0x7FFFFFu, t.y);
    }
}

// ================= dense embedding tables =================

// emb0[r][n][h] = sum_b C0[r,b]*W0[b,n,h], bf16.
__global__ __launch_bounds__(NTHR) void k_emb0(const float* __restrict__ W0, const float* __restrict__ C0,
                                               ushort* __restrict__ emb) {
    int t = threadIdx.x;
    size_t base = (size_t)blockIdx.x * 256 + t;  // n*16+h
    float w[16];
    #pragma unroll
    for (int b = 0; b < 16; ++b) w[b] = W0[(size_t)b * (N_NODES * HD) + base];
    __shared__ float c[N_RELS * 16];
    for (int i = t; i < N_RELS * 16; i += NTHR) c[i] = C0[i];
    __syncthreads();
    for (int r = 0; r < N_RELS; ++r) {
        const float* cr = c + r * 16;
        float v = 0.f;
        #pragma unroll
        for (int b = 0; b < 16; ++b) v = fmaf(cr[b], w[b], v);
        u32 x = __float_as_uint(v);
        x = (x + 0x7fffu + ((x >> 16) & 1u)) >> 16;
        emb[(size_t)r * (N_NODES * HD) + base] = (ushort)x;
    }
}

// gather-accumulate 16-dim bf16 rows by (rel,src), relu-fused, fp32 out.
__global__ __launch_bounds__(NTHR) void k_g16(const uint2* __restrict__ rec, const int* __restrict__ row_ptr,
                                              const ushort* __restrict__ tbl, float* __restrict__ out) {
    int lane = threadIdx.x & 63;
    int g = lane >> 3, l = lane & 7;
    int wave = (blockIdx.x * NTHR + threadIdx.x) >> 6;
    int nw = (gridDim.x * NTHR) >> 6;
    for (int d = wave; d < N_NODES; d += nw) {
        int s0 = row_ptr[d], s1 = row_ptr[d + 1];
        float a0 = 0.f, a1 = 0.f;
        for (int j = s0 + g; j < s1; j += 8) {
            uint2 rc = rec[j];
            int src = rc.x & 0x1FFFF;
            int rel = rc.x >> 17;
            float nm = __uint_as_float(rc.y);
            u32 q = *(const u32*)(tbl + ((size_t)rel * N_NODES + src) * HD + l * 2);
            a0 = fmaf(nm, bl16(q), a0);
            a1 = fmaf(nm, bh16(q), a1);
        }
        a0 += __shfl_xor(a0, 8);  a1 += __shfl_xor(a1, 8);
        a0 += __shfl_xor(a0, 16); a1 += __shfl_xor(a1, 16);
        a0 += __shfl_xor(a0, 32); a1 += __shfl_xor(a1, 32);
        if (lane < 8)
            *(float2*)(out + (size_t)d * HD + l * 2) = make_float2(fmaxf(a0, 0.f), fmaxf(a1, 0.f));
    }
}

// emb1[r][n][o] = sum_i h[n,i]*Wr1[r,i,o], bf16 out.
// 4 nodes/thread: each uniform LDS weight read feeds 4 accumulator sets (ds_read /4).
__global__ __launch_bounds__(NTHR) void k_emb1q(const float* __restrict__ Wr1, const float* __restrict__ h,
                                                ushort* __restrict__ emb) {
    int grp = blockIdx.x / NT4;   // rel group: [grp*RPB1, grp*RPB1+RPB1)
    int tile = blockIdx.x % NT4;
    __shared__ float w[RPB1 * 256];  // 10 KB
    for (int i = threadIdx.x; i < RPB1 * 256; i += NTHR)
        w[i] = Wr1[grp * (RPB1 * 256) + i];
    __syncthreads();
    int n0 = tile * 1024 + threadIdx.x;
    float hv[4][16];
    bool val[4];
    #pragma unroll
    for (int k = 0; k < 4; ++k) {
        int n = n0 + k * 256;
        val[k] = (n < N_NODES);
        if (val[k]) {
            const float4* hp = (const float4*)(h + (size_t)n * HD);
            float4 a0 = hp[0], a1 = hp[1], a2 = hp[2], a3 = hp[3];
            hv[k][0] = a0.x;  hv[k][1] = a0.y;  hv[k][2] = a0.z;  hv[k][3] = a0.w;
            hv[k][4] = a1.x;  hv[k][5] = a1.y;  hv[k][6] = a1.z;  hv[k][7] = a1.w;
            hv[k][8] = a2.x;  hv[k][9] = a2.y;  hv[k][10] = a2.z; hv[k][11] = a2.w;
            hv[k][12] = a3.x; hv[k][13] = a3.y; hv[k][14] = a3.z; hv[k][15] = a3.w;
        } else {
            #pragma unroll
            for (int i = 0; i < 16; ++i) hv[k][i] = 0.f;
        }
    }
    for (int rr = 0; rr < RPB1; ++rr) {
        const float* wr = w + rr * 256;
        float acc[4][16];
        #pragma unroll
        for (int k = 0; k < 4; ++k)
            #pragma unroll
            for (int o = 0; o < 16; ++o) acc[k][o] = 0.f;
        #pragma unroll
        for (int i = 0; i < 16; ++i) {
            const float4* wp = (const float4*)(wr + i * 16);  // uniform -> LDS broadcast
            float4 w0 = wp[0], w1 = wp[1], w2 = wp[2], w3 = wp[3];
            #pragma unroll
            for (int k = 0; k < 4; ++k) {
                float hi = hv[k][i];
                acc[k][0] = fmaf(hi, w0.x, acc[k][0]);   acc[k][1] = fmaf(hi, w0.y, acc[k][1]);
                acc[k][2] = fmaf(hi, w0.z, acc[k][2]);   acc[k][3] = fmaf(hi, w0.w, acc[k][3]);
                acc[k][4] = fmaf(hi, w1.x, acc[k][4]);   acc[k][5] = fmaf(hi, w1.y, acc[k][5]);
                acc[k][6] = fmaf(hi, w1.z, acc[k][6]);   acc[k][7] = fmaf(hi, w1.w, acc[k][7]);
                acc[k][8] = fmaf(hi, w2.x, acc[k][8]);   acc[k][9] = fmaf(hi, w2.y, acc[k][9]);
                acc[k][10] = fmaf(hi, w2.z, acc[k][10]); acc[k][11] = fmaf(hi, w2.w, acc[k][11]);
                acc[k][12] = fmaf(hi, w3.x, acc[k][12]); acc[k][13] = fmaf(hi, w3.y, acc[k][13]);
                acc[k][14] = fmaf(hi, w3.z, acc[k][14]); acc[k][15] = fmaf(hi, w3.w, acc[k][15]);
            }
        }
        int r = grp * RPB1 + rr;
        #pragma unroll
        for (int k = 0; k < 4; ++k) {
            if (!val[k]) continue;
            uint4* op = (uint4*)(emb + ((size_t)r * N_NODES + (n0 + k * 256)) * HD);
            op[0] = make_uint4(cvtpk(acc[k][0], acc[k][1]), cvtpk(acc[k][2], acc[k][3]),
                               cvtpk(acc[k][4], acc[k][5]), cvtpk(acc[k][6], acc[k][7]));
            op[1] = make_uint4(cvtpk(acc[k][8], acc[k][9]), cvtpk(acc[k][10], acc[k][11]),
                               cvtpk(acc[k][12], acc[k][13]), cvtpk(acc[k][14], acc[k][15]));
        }
    }
}

// emb2[r][n][o] = sum_i h[n,i]*Wr2[r,i,o] (o<8), bf16 out. 4 nodes/thread.
__global__ __launch_bounds__(NTHR) void k_emb2q(const float* __restrict__ Wr2, const float* __restrict__ h,
                                                ushort* __restrict__ emb) {
    int grp = blockIdx.x / NT4;   // rel group: [grp*RPB2, grp*RPB2+RPB2)
    int tile = blockIdx.x % NT4;
    __shared__ float w[RPB2 * 128];  // 2.5 KB
    for (int i = threadIdx.x; i < RPB2 * 128; i += NTHR)
        w[i] = Wr2[grp * (RPB2 * 128) + i];
    __syncthreads();
    int n0 = tile * 1024 + threadIdx.x;
    float hv[4][16];
    bool val[4];
    #pragma unroll
    for (int k = 0; k < 4; ++k) {
        int n = n0 + k * 256;
        val[k] = (n < N_NODES);
        if (val[k]) {
            const float4* hp = (const float4*)(h + (size_t)n * HD);
            float4 a0 = hp[0], a1 = hp[1], a2 = hp[2], a3 = hp[3];
            hv[k][0] = a0.x;  hv[k][1] = a0.y;  hv[k][2] = a0.z;  hv[k][3] = a0.w;
            hv[k][4] = a1.x;  hv[k][5] = a1.y;  hv[k][6] = a1.z;  hv[k][7] = a1.w;
            hv[k][8] = a2.x;  hv[k][9] = a2.y;  hv[k][10] = a2.z; hv[k][11] = a2.w;
            hv[k][12] = a3.x; hv[k][13] = a3.y; hv[k][14] = a3.z; hv[k][15] = a3.w;
        } else {
            #pragma unroll
            for (int i = 0; i < 16; ++i) hv[k][i] = 0.f;
        }
    }
    for (int rr = 0; rr < RPB2; ++rr) {
        const float* wr = w + rr * 128;
        float acc[4][8];
        #pragma unroll
        for (int k = 0; k < 4; ++k)
            #pragma unroll
            for (int o = 0; o < 8; ++o) acc[k][o] = 0.f;
        #pragma unroll
        for (int i = 0; i < 16; ++i) {
            const float4* wp = (const float4*)(wr + i * 8);  // uniform -> LDS broadcast
            float4 w0 = wp[0], w1 = wp[1];
            #pragma unroll
            for (int k = 0; k < 4; ++k) {
                float hi = hv[k][i];
                acc[k][0] = fmaf(hi, w0.x, acc[k][0]); acc[k][1] = fmaf(hi, w0.y, acc[k][1]);
                acc[k][2] = fmaf(hi, w0.z, acc[k][2]); acc[k][3] = fmaf(hi, w0.w, acc[k][3]);
                acc[k][4] = fmaf(hi, w1.x, acc[k][4]); acc[k][5] = fmaf(hi, w1.y, acc[k][5]);
                acc[k][6] = fmaf(hi, w1.z, acc[k][6]); acc[k][7] = fmaf(hi, w1.w, acc[k][7]);
            }
        }
        int r = grp * RPB2 + rr;
        #pragma unroll
        for (int k = 0; k < 4; ++k) {
            if (!val[k]) continue;
            *(uint4*)(emb + ((size_t)r * N_NODES + (n0 + k * 256)) * OD) =
                make_uint4(cvtpk(acc[k][0], acc[k][1]), cvtpk(acc[k][2], acc[k][3]),
                           cvtpk(acc[k][4], acc[k][5]), cvtpk(acc[k][6], acc[k][7]));
        }
    }
}

// gather 8-dim bf16 rows + fused softmax. 16 edge-groups x 4 lanes.
__global__ __launch_bounds__(NTHR) void k_g8sm(const uint2* __restrict__ rec, const int* __restrict__ row_ptr,
                                               const ushort* __restrict__ tbl, float* __restrict__ out) {
    int lane = threadIdx.x & 63;
    int g = lane >> 2, l = lane & 3;
    int wave = (blockIdx.x * NTHR + threadIdx.x) >> 6;
    int nw = (gridDim.x * NTHR) >> 6;
    for (int d = wave; d < N_NODES; d += nw) {
        int s0 = row_ptr[d], s1 = row_ptr[d + 1];
        float a0 = 0.f, a1 = 0.f;
        for (int j = s0 + g; j < s1; j += 16) {
            uint2 rc = rec[j];
            int src = rc.x & 0x1FFFF;
            int rel = rc.x >> 17;
            float nm = __uint_as_float(rc.y);
            u32 q = *(const u32*)(tbl + ((size_t)rel * N_NODES + src) * OD + l * 2);
            a0 = fmaf(nm, bl16(q), a0);
            a1 = fmaf(nm, bh16(q), a1);
        }
        a0 += __shfl_xor(a0, 4);  a1 += __shfl_xor(a1, 4);
        a0 += __shfl_xor(a0, 8);  a1 += __shfl_xor(a1, 8);
        a0 += __shfl_xor(a0, 16); a1 += __shfl_xor(a1, 16);
        a0 += __shfl_xor(a0, 32); a1 += __shfl_xor(a1, 32);
        float mm = fmaxf(a0, a1);
        mm = fmaxf(mm, __shfl_xor(mm, 1));
        mm = fmaxf(mm, __shfl_xor(mm, 2));
        float e0 = __expf(a0 - mm), e1 = __expf(a1 - mm);
        float s = e0 + e1;
        s += __shfl_xor(s, 1);
        s += __shfl_xor(s, 2);
        float inv = 1.0f / s;
        if (lane < 4)
            *(float2*)(out + (size_t)d * OD + l * 2) = make_float2(e0 * inv, e1 * inv);
    }
}

// ======= TIER B fallback (atomics, 16.1 MB) =======
#define NBLK 2560

__device__ __forceinline__ void fma4(float* acc, float c, float4 w) {
    acc[0] = fmaf(c, w.x, acc[0]);
    acc[1] = fmaf(c, w.y, acc[1]);
    acc[2] = fmaf(c, w.z, acc[2]);
    acc[3] = fmaf(c, w.w, acc[3]);
}

__global__ __launch_bounds__(NTHR) void k_l0_old(const int* __restrict__ esrc, const int* __restrict__ edst,
                                                 const int* __restrict__ erel, const float* __restrict__ enorm,
                                                 const float* __restrict__ W0, const float* __restrict__ C0,
                                                 float* __restrict__ h0) {
    for (int e = blockIdx.x * NTHR + threadIdx.x; e < E_TOTAL; e += NBLK * NTHR) {
        int s = esrc[e], d = edst[e], r = erel[e];
        float nm = enorm[e];
        const float4* cp = reinterpret_cast<const float4*>(C0 + r * N_BASES);
        float4 c0 = cp[0], c1 = cp[1], c2 = cp[2], c3 = cp[3];
        float coef[16] = {c0.x, c0.y, c0.z, c0.w, c1.x, c1.y, c1.z, c1.w,
                          c2.x, c2.y, c2.z, c2.w, c3.x, c3.y, c3.z, c3.w};
        float acc[16];
        #pragma unroll
        for (int h = 0; h < 16; ++h) acc[h] = 0.f;
        const float* wbase = W0 + (size_t)s * HD;
        #pragma unroll
        for (int b = 0; b < N_BASES; ++b) {
            const float4* wp = reinterpret_cast<const float4*>(wbase + (size_t)b * (N_NODES * HD));
            float cb = coef[b];
            fma4(acc + 0, cb, wp[0]);
            fma4(acc + 4, cb, wp[1]);
            fma4(acc + 8, cb, wp[2]);
            fma4(acc + 12, cb, wp[3]);
        }
        float* outp = h0 + (size_t)d * HD;
        #pragma unroll
        for (int h = 0; h < 16; ++h) atomicAdd(outp + h, nm * acc[h]);
    }
}

__global__ __launch_bounds__(NTHR) void k_l1_old(const int* __restrict__ esrc, const int* __restrict__ edst,
                                                 const int* __restrict__ erel, const float* __restrict__ enorm,
                                                 const float* __restrict__ h0, const float* __restrict__ Wr1,
                                                 float* __restrict__ h1) {
    __shared__ float w[N_RELS * 260];
    for (int i = threadIdx.x; i < N_RELS * 256; i += NTHR) {
        int r = i >> 8, rest = i & 255;
        w[r * 260 + rest] = Wr1[i];
    }
    __syncthreads();
    for (int e = blockIdx.x * NTHR + threadIdx.x; e < E_TOTAL; e += NBLK * NTHR) {
        int s = esrc[e], d = edst[e], r = erel[e];
        float nm = enorm[e];
        const float4* hp = reinterpret_cast<const float4*>(h0 + (size_t)s * HD);
        float4 hv0 = hp[0], hv1 = hp[1], hv2 = hp[2], hv3 = hp[3];
        float hs[16] = {fmaxf(hv0.x, 0.f), fmaxf(hv0.y, 0.f), fmaxf(hv0.z, 0.f), fmaxf(hv0.w, 0.f),
                        fmaxf(hv1.x, 0.f), fmaxf(hv1.y, 0.f), fmaxf(hv1.z, 0.f), fmaxf(hv1.w, 0.f),
                        fmaxf(hv2.x, 0.f), fmaxf(hv2.y, 0.f), fmaxf(hv2.z, 0.f), fmaxf(hv2.w, 0.f),
                        fmaxf(hv3.x, 0.f), fmaxf(hv3.y, 0.f), fmaxf(hv3.z, 0.f), fmaxf(hv3.w, 0.f)};
        float acc[16];
        #pragma unroll
        for (int h = 0; h < 16; ++h) acc[h] = 0.f;
        const float* wr = w + r * 260;
        #pragma unroll
        for (int i = 0; i < 16; ++i) {
            float hi = hs[i];
            const float4* wp = reinterpret_cast<const float4*>(wr + i * 16);
            fma4(acc + 0, hi, wp[0]);
            fma4(acc + 4, hi, wp[1]);
            fma4(acc + 8, hi, wp[2]);
            fma4(acc + 12, hi, wp[3]);
        }
        float* outp = h1 + (size_t)d * HD;
        #pragma unroll
        for (int h = 0; h < 16; ++h) atomicAdd(outp + h, nm * acc[h]);
    }
}

__global__ __launch_bounds__(NTHR) void k_l2_old(const int* __restrict__ esrc, const int* __restrict__ edst,
                                                 const int* __restrict__ erel, const float* __restrict__ enorm,
                                                 const float* __restrict__ h1, const float* __restrict__ Wr2,
                                                 float* __restrict__ h2) {
    __shared__ float w[N_RELS * 132];
    for (int i = threadIdx.x; i < N_RELS * 128; i += NTHR) {
        int r = i >> 7, rest = i & 127;
        w[r * 132 + rest] = Wr2[i];
    }
    __syncthreads();
    for (int e = blockIdx.x * NTHR + threadIdx.x; e < E_TOTAL; e += NBLK * NTHR) {
        int s = esrc[e], d = edst[e], r = erel[e];
        float nm = enorm[e];
        const float4* hp = reinterpret_cast<const float4*>(h1 + (size_t)s * HD);
        float4 hv0 = hp[0], hv1 = hp[1], hv2 = hp[2], hv3 = hp[3];
        float hs[16] = {fmaxf(hv0.x, 0.f), fmaxf(hv0.y, 0.f), fmaxf(hv0.z, 0.f), fmaxf(hv0.w, 0.f),
                        fmaxf(hv1.x, 0.f), fmaxf(hv1.y, 0.f), fmaxf(hv1.z, 0.f), fmaxf(hv1.w, 0.f),
                        fmaxf(hv2.x, 0.f), fmaxf(hv2.y, 0.f), fmaxf(hv2.z, 0.f), fmaxf(hv2.w, 0.f),
                        fmaxf(hv3.x, 0.f), fmaxf(hv3.y, 0.f), fmaxf(hv3.z, 0.f), fmaxf(hv3.w, 0.f)};
        float acc[8];
        #pragma unroll
        for (int h = 0; h < 8; ++h) acc[h] = 0.f;
        const float* wr = w + r * 132;
        #pragma unroll
        for (int i = 0; i < 16; ++i) {
            float hi = hs[i];
            const float4* wp = reinterpret_cast<const float4*>(wr + i * 8);
            fma4(acc + 0, hi, wp[0]);
            fma4(acc + 4, hi, wp[1]);
        }
        float* outp = h2 + (size_t)d * OD;
        #pragma unroll
        for (int h = 0; h < 8; ++h) atomicAdd(outp + h, nm * acc[h]);
    }
}

__global__ __launch_bounds__(NTHR) void k_softmax(const float* __restrict__ h2, float* __restrict__ out) {
    int n = blockIdx.x * NTHR + threadIdx.x;
    if (n >= N_NODES) return;
    const float4* p = reinterpret_cast<const float4*>(h2 + (size_t)n * OD);
    float4 a = p[0], b = p[1];
    float v[8] = {a.x, a.y, a.z, a.w, b.x, b.y, b.z, b.w};
    float m = v[0];
    #pragma unroll
    for (int i = 1; i < 8; ++i) m = fmaxf(m, v[i]);
    float ssum = 0.f;
    #pragma unroll
    for (int i = 0; i < 8; ++i) {
        v[i] = __expf(v[i] - m);
        ssum += v[i];
    }
    float inv = 1.0f / ssum;
    float4* q = reinterpret_cast<float4*>(out + (size_t)n * OD);
    q[0] = make_float4(v[0] * inv, v[1] * inv, v[2] * inv, v[3] * inv);
    q[1] = make_float4(v[4] * inv, v[5] * inv, v[6] * inv, v[7] * inv);
}

// =========================================================================

extern "C" void kernel_launch(void* const* d_in, const int* in_sizes, int n_in,
                              void* d_out, int out_size, void* d_ws, size_t ws_size,
                              hipStream_t stream) {
    const int* esrc = (const int*)d_in[0];
    const int* edst = (const int*)d_in[1];
    const int* erel = (const int*)d_in[2];
    const float* enorm = (const float*)d_in[3];
    const float* W0 = (const float*)d_in[4];
    const float* C0 = (const float*)d_in[5];
    const float* W1 = (const float*)d_in[6];
    const float* C1 = (const float*)d_in[7];
    const float* W2 = (const float*)d_in[8];
    const float* C2 = (const float*)d_in[9];
    const int nsb = (N_NODES + NTHR - 1) / NTHR;  // 391

    if (ws_size >= (size_t)201000000) {
        char* wsb = (char*)d_ws;
        ushort* emb = (ushort*)wsb;                       // 160,000,000 B (L0/L1 tables; L2 table reuses first 80 MB)
        uint2* tmp = (uint2*)wsb;                         //  28,224,000 B (aliases emb; used before emb0)
        uint2* rec = (uint2*)(wsb + 160000000);           //  25,600,000
        float* h0 = (float*)(wsb + 185600000);            //   6,400,000
        float* h1 = (float*)(wsb + 192000000);            //   6,400,000
        float* Wr1 = (float*)(wsb + 198400000);           //      51,200
        float* Wr2 = (float*)(wsb + 198451200);           //      25,600
        int* row_ptr = (int*)(wsb + 198476800);           //     400,004
        int* bhead = (int*)(wsb + 198876804);             //      12,544 (196 x 16-int padded)
        int* bfinal = (int*)(wsb + 198889348);            //         784

        hipMemsetAsync(bhead, 0, NBKT * 16 * sizeof(int), stream);
        k_p1<<<P1_BLOCKS, NTHR, 0, stream>>>(esrc, edst, erel, enorm, bhead, tmp);
        k_bscan<<<1, 256, 0, stream>>>(bhead, bfinal);
        k_p2<<<NBKT, 1024, 0, stream>>>(tmp, bhead, bfinal, rec, row_ptr);
        k_wr<<<75, NTHR, 0, stream>>>(W1, C1, W2, C2, Wr1, Wr2);

        k_emb0<<<N_NODES * HD / NTHR, NTHR, 0, stream>>>(W0, C0, emb);
        k_g16<<<6250, NTHR, 0, stream>>>(rec, row_ptr, emb, h0);
        k_emb1q<<<5 * NT4, NTHR, 0, stream>>>(Wr1, h0, emb);
        k_g16<<<6250, NTHR, 0, stream>>>(rec, row_ptr, emb, h1);
        k_emb2q<<<10 * NT4, NTHR, 0, stream>>>(Wr2, h1, emb);
        k_g8sm<<<6250, NTHR, 0, stream>>>(rec, row_ptr, emb, (float*)d_out);
    } else {
        // ---- Tier B: atomics fallback ----
        float* ws = (float*)d_ws;
        float* h0 = ws;
        float* h1 = ws + 1600000;
        float* h2 = ws + 3200000;
        float* Wr1 = ws + 4000000;
        float* Wr2 = ws + 4012800;

        hipMemsetAsync(h0, 0, (size_t)4000000 * sizeof(float), stream);
        k_wr<<<75, NTHR, 0, stream>>>(W1, C1, W2, C2, Wr1, Wr2);
        k_l0_old<<<NBLK, NTHR, 0, stream>>>(esrc, edst, erel, enorm, W0, C0, h0);
        k_l1_old<<<NBLK, NTHR, 0, stream>>>(esrc, edst, erel, enorm, h0, Wr1, h1);
        k_l2_old<<<NBLK, NTHR, 0, stream>>>(esrc, edst, erel, enorm, h1, Wr2, h2);
        k_softmax<<<nsb, NTHR, 0, stream>>>(h2, (float*)d_out);
    }
}